// Round 4
// baseline (6516.947 us; speedup 1.0000x reference)
//
#include <hip/hip_runtime.h>
#include <stdint.h>

// Problem constants (fixed by reference)
#define B_   16
#define S_   2048
#define DIN  512
#define DH   1024
#define DOUT 10

typedef unsigned short u16;
typedef unsigned int   u32;

typedef __bf16 bf16_t;
typedef bf16_t bf16x8 __attribute__((ext_vector_type(8)));
typedef float  f32x4  __attribute__((ext_vector_type(4)));

__device__ __forceinline__ float b2f(u16 u) {
    union { u32 i; float f; } v; v.i = ((u32)u) << 16; return v.f;
}
__device__ __forceinline__ u16 f2b(float f) {
    union { float f; u32 i; } v; v.f = f;
    u32 u = v.i;
    u32 r = (u + 0x7FFFu + ((u >> 16) & 1u)) >> 16;  // RNE
    return (u16)r;
}
__device__ __forceinline__ u32 pack2(float a, float b) {
    return (u32)f2b(a) | ((u32)f2b(b) << 16);
}

__device__ __forceinline__ f32x4 mfma16(bf16x8 a, bf16x8 b, f32x4 c) {
    return __builtin_amdgcn_mfma_f32_16x16x32_bf16(a, b, c, 0, 0, 0);
}

// load 8 contiguous elements at element-index eidx as packed bf16x8 (uint4)
template<bool F32>
__device__ __forceinline__ uint4 ld8(const void* base, size_t eidx) {
    if constexpr (F32) {
        const float* p = (const float*)base + eidx;
        float4 f0 = *(const float4*)p;
        float4 f1 = *(const float4*)(p + 4);
        uint4 r;
        r.x = pack2(f0.x, f0.y); r.y = pack2(f0.z, f0.w);
        r.z = pack2(f1.x, f1.y); r.w = pack2(f1.z, f1.w);
        return r;
    } else {
        return *(const uint4*)((const u16*)base + eidx);
    }
}

// ---------------------------------------------------------------------------
// C[M,N] = relu(A[M,K] @ Bt[N,K]^T + bias[N]); A f32 or bf16 (AF32), Bt bf16,
// bias f32, C bf16, fp32 accum. 128x128 tile, BK=32, 4 waves, 4x4 MFMA/wave.
// Synchronous staging (reg prefetch one K-slice ahead).
// ---------------------------------------------------------------------------
template<bool AF32>
__global__ __launch_bounds__(256) void gemm_bt_bias_relu(
    const void* __restrict__ A, const u16* __restrict__ Bt,
    const float* __restrict__ bias, u16* __restrict__ C,
    int M, int N, int K, int do_relu)
{
    __shared__ __attribute__((aligned(16))) u16 As[128 * 32];
    __shared__ __attribute__((aligned(16))) u16 Bs[128 * 32];

    const int tid  = threadIdx.x;
    const int lane = tid & 63;
    const int w    = tid >> 6;       // wave 0..3
    const int wm   = w >> 1, wn = w & 1;
    const int quad = lane >> 4, l15 = lane & 15;

    const int m0 = blockIdx.x * 128;
    const int n0 = blockIdx.y * 128;

    // tile = 512 chunks of 8 elements; thread handles chunks c0=tid, c1=tid+256
    const int c0 = tid, c1 = tid + 256;
    size_t eA0 = (size_t)(m0 + (c0 >> 2)) * K + (c0 & 3) * 8;
    size_t eA1 = (size_t)(m0 + (c1 >> 2)) * K + (c1 & 3) * 8;
    size_t eB0 = (size_t)(n0 + (c0 >> 2)) * K + (c0 & 3) * 8;
    size_t eB1 = (size_t)(n0 + (c1 >> 2)) * K + (c1 & 3) * 8;

    f32x4 acc[4][4];
#pragma unroll
    for (int i = 0; i < 4; ++i)
#pragma unroll
        for (int j = 0; j < 4; ++j) acc[i][j] = (f32x4){0.f, 0.f, 0.f, 0.f};

    uint4 va0 = ld8<AF32>(A, eA0), va1 = ld8<AF32>(A, eA1);
    uint4 vb0 = ld8<false>(Bt, eB0), vb1 = ld8<false>(Bt, eB1);

    const int nk = K >> 5;
    for (int kk = 0; kk < nk; ++kk) {
        __syncthreads();
        *(uint4*)&As[c0 * 8] = va0;
        *(uint4*)&As[c1 * 8] = va1;
        *(uint4*)&Bs[c0 * 8] = vb0;
        *(uint4*)&Bs[c1 * 8] = vb1;
        if (kk + 1 < nk) {
            eA0 += 32; eA1 += 32; eB0 += 32; eB1 += 32;
            va0 = ld8<AF32>(A, eA0); va1 = ld8<AF32>(A, eA1);
            vb0 = ld8<false>(Bt, eB0); vb1 = ld8<false>(Bt, eB1);
        }
        __syncthreads();
        bf16x8 af[4], bfr[4];
#pragma unroll
        for (int i = 0; i < 4; ++i)
            af[i] = *(const bf16x8*)&As[(wm * 64 + i * 16 + l15) * 32 + quad * 8];
#pragma unroll
        for (int j = 0; j < 4; ++j)
            bfr[j] = *(const bf16x8*)&Bs[(wn * 64 + j * 16 + l15) * 32 + quad * 8];
#pragma unroll
        for (int i = 0; i < 4; ++i)
#pragma unroll
            for (int j = 0; j < 4; ++j)
                acc[i][j] = mfma16(af[i], bfr[j], acc[i][j]);
    }

    // epilogue: C row = quad*4 + reg, col = lane&15 (m89-verified C layout)
    const int r0 = quad * 4;
#pragma unroll
    for (int j = 0; j < 4; ++j) {
        int col = n0 + wn * 64 + j * 16 + l15;
        float bv = bias[col];
#pragma unroll
        for (int i = 0; i < 4; ++i) {
            int rowb = m0 + wm * 64 + i * 16 + r0;
#pragma unroll
            for (int r = 0; r < 4; ++r) {
                float v = acc[i][j][r] + bv;
                if (do_relu) v = fmaxf(v, 0.f);
                C[(size_t)(rowb + r) * N + col] = f2b(v);
            }
        }
    }
}

// ---------------------------------------------------------------------------
// transpose + f32->bf16 convert: in f32 [R][C] -> out bf16 [C][R]. block (32,8)
// ---------------------------------------------------------------------------
__global__ __launch_bounds__(256) void transpose_cvt(
    const float* __restrict__ in, u16* __restrict__ out, int R, int C)
{
    __shared__ u16 t[32][33];
    int c0 = blockIdx.x * 32, r0 = blockIdx.y * 32;
    int tx = threadIdx.x, ty = threadIdx.y;
#pragma unroll
    for (int i = 0; i < 4; ++i)
        t[ty + i * 8][tx] = f2b(in[(size_t)(r0 + ty + i * 8) * C + c0 + tx]);
    __syncthreads();
#pragma unroll
    for (int i = 0; i < 4; ++i)
        out[(size_t)(c0 + ty + i * 8) * R + r0 + tx] = t[tx][ty + i * 8];
}

// bf16 transpose (for h -> hT), in [R][C] -> out [C][R]
__global__ __launch_bounds__(256) void transpose_k(
    const u16* __restrict__ in, u16* __restrict__ out, int R, int C)
{
    __shared__ u16 t[32][33];
    int c0 = blockIdx.x * 32, r0 = blockIdx.y * 32;
    int tx = threadIdx.x, ty = threadIdx.y;
#pragma unroll
    for (int i = 0; i < 4; ++i)
        t[ty + i * 8][tx] = in[(size_t)(r0 + ty + i * 8) * C + c0 + tx];
    __syncthreads();
#pragma unroll
    for (int i = 0; i < 4; ++i)
        out[(size_t)(c0 + ty + i * 8) * R + r0 + tx] = t[tx][ty + i * 8];
}

// ---------------------------------------------------------------------------
// Fused causal attention, online softmax (flash), SINGLE batch. grid (S/16).
// bf16 in (hb [S][DH], hTb [DH][S]) -> bf16 ctx [S][DH].
// ---------------------------------------------------------------------------
#define MASKVAL (-3.0e4f)
__global__ __launch_bounds__(256) void flash_attn(
    const u16* __restrict__ hb, const u16* __restrict__ hTb, u16* __restrict__ cb)
{
    __shared__ __attribute__((aligned(16))) u16 Qs[16][1032];  // pad 8
    __shared__ __attribute__((aligned(16))) u16 Ps[16][136];
    __shared__ float red_max[4][16];
    __shared__ float red_sum[4][16];
    __shared__ float m_s[16], alpha_s[16], l_s[16];

    const int tid  = threadIdx.x;
    const int lane = tid & 63, w = tid >> 6;
    const int quad = lane >> 4, l15 = lane & 15;
    const int q0 = blockIdx.x * 16;
    const int d0 = w * 256;

    for (int idx = tid; idx < 16 * 128; idx += 256) {
        int row = idx >> 7, c8 = (idx & 127) * 8;
        *(uint4*)&Qs[row][c8] = *(const uint4*)&hb[(size_t)(q0 + row) * DH + c8];
    }
    if (tid < 16) { m_s[tid] = MASKVAL; l_s[tid] = 0.f; }
    f32x4 O[16];
#pragma unroll
    for (int n = 0; n < 16; ++n) O[n] = (f32x4){0.f, 0.f, 0.f, 0.f};
    __syncthreads();

    const int nwin = (q0 >> 7) + 1;
    for (int win = 0; win < nwin; ++win) {
        const int kv0 = win << 7;
        const int kvw = kv0 + w * 32;

        f32x4 s0 = (f32x4){0.f,0.f,0.f,0.f}, s1 = (f32x4){0.f,0.f,0.f,0.f};
#pragma unroll 4
        for (int ks = 0; ks < 32; ++ks) {
            bf16x8 aq = *(const bf16x8*)&Qs[l15][ks * 32 + quad * 8];
            const u16* kb = &hb[(size_t)(kvw + l15) * DH + ks * 32 + quad * 8];
            bf16x8 k0v = *(const bf16x8*)kb;
            bf16x8 k1v = *(const bf16x8*)(kb + (size_t)16 * DH);
            s0 = mfma16(aq, k0v, s0);
            s1 = mfma16(aq, k1v, s1);
        }
        float vmax[4];
#pragma unroll
        for (int r = 0; r < 4; ++r) {
            int q = q0 + quad * 4 + r;
            if (kvw + l15      > q) s0[r] = MASKVAL;
            if (kvw + 16 + l15 > q) s1[r] = MASKVAL;
            vmax[r] = fmaxf(s0[r], s1[r]);
        }
#pragma unroll
        for (int off = 8; off >= 1; off >>= 1)
#pragma unroll
            for (int r = 0; r < 4; ++r)
                vmax[r] = fmaxf(vmax[r], __shfl_xor(vmax[r], off, 64));
        if (l15 == 0)
#pragma unroll
            for (int r = 0; r < 4; ++r) red_max[w][quad * 4 + r] = vmax[r];
        __syncthreads();
        if (tid < 16) {
            float mo = m_s[tid];
            float mn = fmaxf(mo, fmaxf(fmaxf(red_max[0][tid], red_max[1][tid]),
                                       fmaxf(red_max[2][tid], red_max[3][tid])));
            m_s[tid] = mn;
            alpha_s[tid] = __expf(mo - mn);
        }
        __syncthreads();
        float mrow[4], arow[4], vsum[4];
#pragma unroll
        for (int r = 0; r < 4; ++r) { mrow[r] = m_s[quad*4+r]; arow[r] = alpha_s[quad*4+r]; }
#pragma unroll
        for (int r = 0; r < 4; ++r) {
            float p0 = __expf(s0[r] - mrow[r]);
            float p1 = __expf(s1[r] - mrow[r]);
            vsum[r] = p0 + p1;
            Ps[quad*4+r][w*32 + l15]      = f2b(p0);
            Ps[quad*4+r][w*32 + 16 + l15] = f2b(p1);
        }
#pragma unroll
        for (int off = 8; off >= 1; off >>= 1)
#pragma unroll
            for (int r = 0; r < 4; ++r)
                vsum[r] += __shfl_xor(vsum[r], off, 64);
        if (l15 == 0)
#pragma unroll
            for (int r = 0; r < 4; ++r) red_sum[w][quad * 4 + r] = vsum[r];
#pragma unroll
        for (int n = 0; n < 16; ++n)
#pragma unroll
            for (int r = 0; r < 4; ++r) O[n][r] *= arow[r];
        __syncthreads();
        if (tid < 16)
            l_s[tid] = l_s[tid] * alpha_s[tid] + red_sum[0][tid] + red_sum[1][tid]
                     + red_sum[2][tid] + red_sum[3][tid];
        for (int ks = 0; ks < 4; ++ks) {
            bf16x8 pa = *(const bf16x8*)&Ps[l15][ks * 32 + quad * 8];
            const u16* vb = &hTb[(size_t)(d0 + l15) * S_ + kv0 + ks * 32 + quad * 8];
#pragma unroll
            for (int n = 0; n < 16; ++n) {
                bf16x8 bv = *(const bf16x8*)(vb + (size_t)n * 16 * S_);
                O[n] = mfma16(pa, bv, O[n]);
            }
        }
    }
    __syncthreads();
    float linv[4];
#pragma unroll
    for (int r = 0; r < 4; ++r) linv[r] = 1.0f / l_s[quad * 4 + r];
#pragma unroll
    for (int n = 0; n < 16; ++n) {
        int col = d0 + n * 16 + l15;
#pragma unroll
        for (int r = 0; r < 4; ++r)
            cb[(size_t)(q0 + quad * 4 + r) * DH + col] = f2b(O[n][r] * linv[r]);
    }
}

// ---------------------------------------------------------------------------
// head: out[row,:] = log_softmax(o[row,:] @ W4 + b4). One wave per row.
// o bf16 [rows][512], W4/b4 f32, out f32.
// ---------------------------------------------------------------------------
__global__ __launch_bounds__(256) void head_logsoftmax(
    const u16* __restrict__ o, const float* __restrict__ W4,
    const float* __restrict__ b4, float* __restrict__ out)
{
    __shared__ float W4s[DIN * DOUT];
    __shared__ float b4s[DOUT];
    const int tid = threadIdx.x;
    for (int i = tid; i < DIN * DOUT; i += 256) W4s[i] = W4[i];
    if (tid < DOUT) b4s[tid] = b4[tid];
    __syncthreads();
    const int lane = tid & 63, w = tid >> 6;
    const size_t row = (size_t)blockIdx.x * 4 + w;
    const uint4 ov = *(const uint4*)&o[row * DIN + lane * 8];
    const u32* ou = (const u32*)&ov;
    float oc[8];
#pragma unroll
    for (int i = 0; i < 4; ++i) {
        oc[2*i]   = b2f((u16)(ou[i] & 0xFFFFu));
        oc[2*i+1] = b2f((u16)(ou[i] >> 16));
    }
    float acc[DOUT];
#pragma unroll
    for (int c = 0; c < DOUT; ++c) acc[c] = 0.f;
#pragma unroll
    for (int i = 0; i < 8; ++i) {
        int k = lane * 8 + i;
        float x = oc[i];
#pragma unroll
        for (int c = 0; c < DOUT; ++c) acc[c] += x * W4s[k * DOUT + c];
    }
#pragma unroll
    for (int off = 32; off >= 1; off >>= 1)
#pragma unroll
        for (int c = 0; c < DOUT; ++c) acc[c] += __shfl_xor(acc[c], off, 64);
    float mx = -1e30f;
#pragma unroll
    for (int c = 0; c < DOUT; ++c) { acc[c] += b4s[c]; mx = fmaxf(mx, acc[c]); }
    float sum = 0.f;
#pragma unroll
    for (int c = 0; c < DOUT; ++c) sum += __expf(acc[c] - mx);
    float lse = mx + logf(sum);
    if (lane == 0) {
#pragma unroll
        for (int c = 0; c < DOUT; ++c) out[row * DOUT + c] = acc[c] - lse;
    }
}

// ---------------------------------------------------------------------------
// Workspace (peak ~84 MiB):
//   [0, 64Mi)        h  bf16 [32768,1024]
//   [64Mi, 80Mi)     h1_buf bf16 (8192x1024) -- overlaid: hT_b | ctx_b | o_b
//   [80Mi, ~84Mi)    W1t, W2t, W3t (bf16)
// ---------------------------------------------------------------------------
extern "C" void kernel_launch(void* const* d_in, const int* in_sizes, int n_in,
                              void* d_out, int out_size, void* d_ws, size_t ws_size,
                              hipStream_t stream) {
    const float* x  = (const float*)d_in[0];   // f32 per reference
    const float* gv = (const float*)d_in[1];
    const float* uv = (const float*)d_in[2];
    const float* W1 = (const float*)d_in[3];
    const float* b1 = (const float*)d_in[4];
    const float* W2 = (const float*)d_in[5];
    const float* b2 = (const float*)d_in[6];
    const float* W3 = (const float*)d_in[7];
    const float* b3 = (const float*)d_in[8];
    const float* W4 = (const float*)d_in[9];
    const float* b4 = (const float*)d_in[10];
    float* out = (float*)d_out;                // f32 per reference

    char* ws = (char*)d_ws;
    u16* h      = (u16*)(ws);                                   // 64 MiB
    u16* h1_buf = (u16*)(ws + (size_t)67108864);                // 16 MiB
    u16* hT_b   = h1_buf;                                       // 4 MiB
    u16* ctx_b  = (u16*)(ws + (size_t)67108864 + 4194304);      // 4 MiB
    u16* o_b    = (u16*)(ws + (size_t)67108864 + 8388608);      // 2 MiB
    u16* W1t    = (u16*)(ws + (size_t)83886080);                // 1 MiB
    u16* W2t    = W1t + 512 * 1024;                             // 2 MiB
    u16* W3t    = W2t + 1024 * 1024;                            // 1 MiB

    // weight transposes (f32 -> bf16)
    transpose_cvt<<<dim3(32, 16), dim3(32, 8), 0, stream>>>(W1, W1t, 512, 1024);
    transpose_cvt<<<dim3(32, 32), dim3(32, 8), 0, stream>>>(W2, W2t, 1024, 1024);
    transpose_cvt<<<dim3(16, 32), dim3(32, 8), 0, stream>>>(W3, W3t, 1024, 512);

    // GEMM1 (A=f32 x) -> GEMM2, chunked over 4 x 8192 rows through h1_buf
    for (int c = 0; c < 4; ++c) {
        const float* xc = x + (size_t)c * 8192 * DIN;
        u16*         hc = h + (size_t)c * 8192 * DH;
        gemm_bt_bias_relu<true ><<<dim3(64, 8), 256, 0, stream>>>(xc, W1t, b1, h1_buf,
                                                                  8192, 1024, 512, 1);
        gemm_bt_bias_relu<false><<<dim3(64, 8), 256, 0, stream>>>(h1_buf, W2t, b2, hc,
                                                                  8192, 1024, 1024, 1);
    }

    // per-batch: transpose -> flash -> GEMM3 -> head
    for (int b = 0; b < B_; ++b) {
        const u16* hb = h + (size_t)b * S_ * DH;
        transpose_k<<<dim3(32, 64), dim3(32, 8), 0, stream>>>(hb, hT_b, 2048, 1024);
        flash_attn<<<dim3(128), 256, 0, stream>>>(hb, hT_b, ctx_b);
        gemm_bt_bias_relu<false><<<dim3(16, 4), 256, 0, stream>>>(ctx_b, W3t, b3, o_b,
                                                                  2048, 512, 1024, 1);
        head_logsoftmax<<<512, 256, 0, stream>>>(o_b, W4, b4,
                                                 out + (size_t)b * S_ * DOUT);
    }

    // pass-throughs (f32): game/user are (16,10,1024) = 163840 elements each
    size_t n_gv = (size_t)in_sizes[1], n_uv = (size_t)in_sizes[2];
    size_t o0 = (size_t)out_size - n_gv - n_uv;
    hipMemcpyAsync(out + o0,        gv, n_gv * 4, hipMemcpyDeviceToDevice, stream);
    hipMemcpyAsync(out + o0 + n_gv, uv, n_uv * 4, hipMemcpyDeviceToDevice, stream);
}

// Round 5
// 1789.557 us; speedup vs baseline: 3.6417x; 3.6417x over previous
//
#include <hip/hip_runtime.h>
#include <stdint.h>

// Problem constants (fixed by reference)
#define B_   16
#define S_   2048
#define DIN  512
#define DH   1024
#define DOUT 10

typedef unsigned short u16;
typedef unsigned int   u32;

typedef __bf16 bf16_t;
typedef bf16_t bf16x8 __attribute__((ext_vector_type(8)));
typedef float  f32x4  __attribute__((ext_vector_type(4)));

__device__ __forceinline__ float b2f(u16 u) {
    union { u32 i; float f; } v; v.i = ((u32)u) << 16; return v.f;
}
__device__ __forceinline__ u16 f2b(float f) {
    union { float f; u32 i; } v; v.f = f;
    u32 u = v.i;
    u32 r = (u + 0x7FFFu + ((u >> 16) & 1u)) >> 16;  // RNE
    return (u16)r;
}
__device__ __forceinline__ u32 pack2(float a, float b) {
    return (u32)f2b(a) | ((u32)f2b(b) << 16);
}

__device__ __forceinline__ f32x4 mfma16(bf16x8 a, bf16x8 b, f32x4 c) {
    return __builtin_amdgcn_mfma_f32_16x16x32_bf16(a, b, c, 0, 0, 0);
}

// load 8 contiguous elements at element-index eidx as packed bf16x8 (uint4)
template<bool F32>
__device__ __forceinline__ uint4 ld8(const void* base, size_t eidx) {
    if constexpr (F32) {
        const float* p = (const float*)base + eidx;
        float4 f0 = *(const float4*)p;
        float4 f1 = *(const float4*)(p + 4);
        uint4 r;
        r.x = pack2(f0.x, f0.y); r.y = pack2(f0.z, f0.w);
        r.z = pack2(f1.x, f1.y); r.w = pack2(f1.z, f1.w);
        return r;
    } else {
        return *(const uint4*)((const u16*)base + eidx);
    }
}

// ---------------------------------------------------------------------------
// C[M,N] = relu(A[M,K] @ Bt[N,K]^T + bias[N]); A f32 or bf16 (AF32), Bt bf16,
// bias f32, C bf16, fp32 accum. 128x128 tile, BK=32, 4 waves, 4x4 MFMA/wave.
// ---------------------------------------------------------------------------
template<bool AF32>
__global__ __launch_bounds__(256) void gemm_bt_bias_relu(
    const void* __restrict__ A, const u16* __restrict__ Bt,
    const float* __restrict__ bias, u16* __restrict__ C,
    int M, int N, int K, int do_relu)
{
    __shared__ __attribute__((aligned(16))) u16 As[128 * 32];
    __shared__ __attribute__((aligned(16))) u16 Bs[128 * 32];

    const int tid  = threadIdx.x;
    const int lane = tid & 63;
    const int w    = tid >> 6;       // wave 0..3
    const int wm   = w >> 1, wn = w & 1;
    const int quad = lane >> 4, l15 = lane & 15;

    const int m0 = blockIdx.x * 128;
    const int n0 = blockIdx.y * 128;

    const int c0 = tid, c1 = tid + 256;
    size_t eA0 = (size_t)(m0 + (c0 >> 2)) * K + (c0 & 3) * 8;
    size_t eA1 = (size_t)(m0 + (c1 >> 2)) * K + (c1 & 3) * 8;
    size_t eB0 = (size_t)(n0 + (c0 >> 2)) * K + (c0 & 3) * 8;
    size_t eB1 = (size_t)(n0 + (c1 >> 2)) * K + (c1 & 3) * 8;

    f32x4 acc[4][4];
#pragma unroll
    for (int i = 0; i < 4; ++i)
#pragma unroll
        for (int j = 0; j < 4; ++j) acc[i][j] = (f32x4){0.f, 0.f, 0.f, 0.f};

    uint4 va0 = ld8<AF32>(A, eA0), va1 = ld8<AF32>(A, eA1);
    uint4 vb0 = ld8<false>(Bt, eB0), vb1 = ld8<false>(Bt, eB1);

    const int nk = K >> 5;
    for (int kk = 0; kk < nk; ++kk) {
        __syncthreads();
        *(uint4*)&As[c0 * 8] = va0;
        *(uint4*)&As[c1 * 8] = va1;
        *(uint4*)&Bs[c0 * 8] = vb0;
        *(uint4*)&Bs[c1 * 8] = vb1;
        if (kk + 1 < nk) {
            eA0 += 32; eA1 += 32; eB0 += 32; eB1 += 32;
            va0 = ld8<AF32>(A, eA0); va1 = ld8<AF32>(A, eA1);
            vb0 = ld8<false>(Bt, eB0); vb1 = ld8<false>(Bt, eB1);
        }
        __syncthreads();
        bf16x8 af[4], bfr[4];
#pragma unroll
        for (int i = 0; i < 4; ++i)
            af[i] = *(const bf16x8*)&As[(wm * 64 + i * 16 + l15) * 32 + quad * 8];
#pragma unroll
        for (int j = 0; j < 4; ++j)
            bfr[j] = *(const bf16x8*)&Bs[(wn * 64 + j * 16 + l15) * 32 + quad * 8];
#pragma unroll
        for (int i = 0; i < 4; ++i)
#pragma unroll
            for (int j = 0; j < 4; ++j)
                acc[i][j] = mfma16(af[i], bfr[j], acc[i][j]);
    }

    const int r0 = quad * 4;
#pragma unroll
    for (int j = 0; j < 4; ++j) {
        int col = n0 + wn * 64 + j * 16 + l15;
        float bv = bias[col];
#pragma unroll
        for (int i = 0; i < 4; ++i) {
            int rowb = m0 + wm * 64 + i * 16 + r0;
#pragma unroll
            for (int r = 0; r < 4; ++r) {
                float v = acc[i][j][r] + bv;
                if (do_relu) v = fmaxf(v, 0.f);
                C[(size_t)(rowb + r) * N + col] = f2b(v);
            }
        }
    }
}

// ---------------------------------------------------------------------------
// transpose + f32->bf16 convert: in f32 [R][C] -> out bf16 [C][R]. block (32,8)
// ---------------------------------------------------------------------------
__global__ __launch_bounds__(256) void transpose_cvt(
    const float* __restrict__ in, u16* __restrict__ out, int R, int C)
{
    __shared__ u16 t[32][33];
    int c0 = blockIdx.x * 32, r0 = blockIdx.y * 32;
    int tx = threadIdx.x, ty = threadIdx.y;
#pragma unroll
    for (int i = 0; i < 4; ++i)
        t[ty + i * 8][tx] = f2b(in[(size_t)(r0 + ty + i * 8) * C + c0 + tx]);
    __syncthreads();
#pragma unroll
    for (int i = 0; i < 4; ++i)
        out[(size_t)(c0 + ty + i * 8) * R + r0 + tx] = t[tx][ty + i * 8];
}

// batched bf16 transpose: in [z][R][C] -> out [z][C][R]. block (32,8)
__global__ __launch_bounds__(256) void transpose_b(
    const u16* __restrict__ in, u16* __restrict__ out, int R, int C)
{
    __shared__ u16 t[32][33];
    const u16* ip = in  + (size_t)blockIdx.z * R * C;
    u16*       op = out + (size_t)blockIdx.z * R * C;
    int c0 = blockIdx.x * 32, r0 = blockIdx.y * 32;
    int tx = threadIdx.x, ty = threadIdx.y;
#pragma unroll
    for (int i = 0; i < 4; ++i)
        t[ty + i * 8][tx] = ip[(size_t)(r0 + ty + i * 8) * C + c0 + tx];
    __syncthreads();
#pragma unroll
    for (int i = 0; i < 4; ++i)
        op[(size_t)(c0 + ty + i * 8) * R + r0 + tx] = t[tx][ty + i * 8];
}

// ---------------------------------------------------------------------------
// Fused causal attention, online softmax (flash). grid (S/16, nb), 256 thr.
// batch = blockIdx.y (strides S_*DH). q-tiles dispatched heavy-first.
// ---------------------------------------------------------------------------
#define MASKVAL (-3.0e4f)
__global__ __launch_bounds__(256) void flash_attn(
    const u16* __restrict__ h, const u16* __restrict__ hT, u16* __restrict__ ctx)
{
    __shared__ __attribute__((aligned(16))) u16 Qs[16][1032];  // pad 8
    __shared__ __attribute__((aligned(16))) u16 Ps[16][136];
    __shared__ float red_max[4][16];
    __shared__ float red_sum[4][16];
    __shared__ float m_s[16], alpha_s[16], l_s[16];

    const int tid  = threadIdx.x;
    const int lane = tid & 63, w = tid >> 6;
    const int quad = lane >> 4, l15 = lane & 15;
    const int q0 = (gridDim.x - 1 - blockIdx.x) * 16;   // heavy tiles first
    const size_t boff = (size_t)blockIdx.y * S_ * DH;
    const u16* hb  = h   + boff;
    const u16* hTb = hT  + boff;
    u16*       cb  = ctx + boff;
    const int d0 = w * 256;

    for (int idx = tid; idx < 16 * 128; idx += 256) {
        int row = idx >> 7, c8 = (idx & 127) * 8;
        *(uint4*)&Qs[row][c8] = *(const uint4*)&hb[(size_t)(q0 + row) * DH + c8];
    }
    if (tid < 16) { m_s[tid] = MASKVAL; l_s[tid] = 0.f; }
    f32x4 O[16];
#pragma unroll
    for (int n = 0; n < 16; ++n) O[n] = (f32x4){0.f, 0.f, 0.f, 0.f};
    __syncthreads();

    const int nwin = (q0 >> 7) + 1;
    for (int win = 0; win < nwin; ++win) {
        const int kv0 = win << 7;
        const int kvw = kv0 + w * 32;

        f32x4 s0 = (f32x4){0.f,0.f,0.f,0.f}, s1 = (f32x4){0.f,0.f,0.f,0.f};
#pragma unroll 4
        for (int ks = 0; ks < 32; ++ks) {
            bf16x8 aq = *(const bf16x8*)&Qs[l15][ks * 32 + quad * 8];
            const u16* kb = &hb[(size_t)(kvw + l15) * DH + ks * 32 + quad * 8];
            bf16x8 k0v = *(const bf16x8*)kb;
            bf16x8 k1v = *(const bf16x8*)(kb + (size_t)16 * DH);
            s0 = mfma16(aq, k0v, s0);
            s1 = mfma16(aq, k1v, s1);
        }
        float vmax[4];
#pragma unroll
        for (int r = 0; r < 4; ++r) {
            int q = q0 + quad * 4 + r;
            if (kvw + l15      > q) s0[r] = MASKVAL;
            if (kvw + 16 + l15 > q) s1[r] = MASKVAL;
            vmax[r] = fmaxf(s0[r], s1[r]);
        }
#pragma unroll
        for (int off = 8; off >= 1; off >>= 1)
#pragma unroll
            for (int r = 0; r < 4; ++r)
                vmax[r] = fmaxf(vmax[r], __shfl_xor(vmax[r], off, 64));
        if (l15 == 0)
#pragma unroll
            for (int r = 0; r < 4; ++r) red_max[w][quad * 4 + r] = vmax[r];
        __syncthreads();
        if (tid < 16) {
            float mo = m_s[tid];
            float mn = fmaxf(mo, fmaxf(fmaxf(red_max[0][tid], red_max[1][tid]),
                                       fmaxf(red_max[2][tid], red_max[3][tid])));
            m_s[tid] = mn;
            alpha_s[tid] = __expf(mo - mn);
        }
        __syncthreads();
        float mrow[4], arow[4], vsum[4];
#pragma unroll
        for (int r = 0; r < 4; ++r) { mrow[r] = m_s[quad*4+r]; arow[r] = alpha_s[quad*4+r]; }
#pragma unroll
        for (int r = 0; r < 4; ++r) {
            float p0 = __expf(s0[r] - mrow[r]);
            float p1 = __expf(s1[r] - mrow[r]);
            vsum[r] = p0 + p1;
            Ps[quad*4+r][w*32 + l15]      = f2b(p0);
            Ps[quad*4+r][w*32 + 16 + l15] = f2b(p1);
        }
#pragma unroll
        for (int off = 8; off >= 1; off >>= 1)
#pragma unroll
            for (int r = 0; r < 4; ++r)
                vsum[r] += __shfl_xor(vsum[r], off, 64);
        if (l15 == 0)
#pragma unroll
            for (int r = 0; r < 4; ++r) red_sum[w][quad * 4 + r] = vsum[r];
#pragma unroll
        for (int n = 0; n < 16; ++n)
#pragma unroll
            for (int r = 0; r < 4; ++r) O[n][r] *= arow[r];
        __syncthreads();
        if (tid < 16)
            l_s[tid] = l_s[tid] * alpha_s[tid] + red_sum[0][tid] + red_sum[1][tid]
                     + red_sum[2][tid] + red_sum[3][tid];
        for (int ks = 0; ks < 4; ++ks) {
            bf16x8 pa = *(const bf16x8*)&Ps[l15][ks * 32 + quad * 8];
            const u16* vb = &hTb[(size_t)(d0 + l15) * S_ + kv0 + ks * 32 + quad * 8];
#pragma unroll
            for (int n = 0; n < 16; ++n) {
                bf16x8 bv = *(const bf16x8*)(vb + (size_t)n * 16 * S_);
                O[n] = mfma16(pa, bv, O[n]);
            }
        }
    }
    __syncthreads();
    float linv[4];
#pragma unroll
    for (int r = 0; r < 4; ++r) linv[r] = 1.0f / l_s[quad * 4 + r];
#pragma unroll
    for (int n = 0; n < 16; ++n) {
        int col = d0 + n * 16 + l15;
#pragma unroll
        for (int r = 0; r < 4; ++r)
            cb[(size_t)(q0 + quad * 4 + r) * DH + col] = f2b(O[n][r] * linv[r]);
    }
}

// ---------------------------------------------------------------------------
// head: out[row,:] = log_softmax(o[row,:] @ W4 + b4). One wave per row.
// o bf16 [rows][512], W4/b4 f32, out f32.
// ---------------------------------------------------------------------------
__global__ __launch_bounds__(256) void head_logsoftmax(
    const u16* __restrict__ o, const float* __restrict__ W4,
    const float* __restrict__ b4, float* __restrict__ out)
{
    __shared__ float W4s[DIN * DOUT];
    __shared__ float b4s[DOUT];
    const int tid = threadIdx.x;
    for (int i = tid; i < DIN * DOUT; i += 256) W4s[i] = W4[i];
    if (tid < DOUT) b4s[tid] = b4[tid];
    __syncthreads();
    const int lane = tid & 63, w = tid >> 6;
    const size_t row = (size_t)blockIdx.x * 4 + w;
    const uint4 ov = *(const uint4*)&o[row * DIN + lane * 8];
    const u32* ou = (const u32*)&ov;
    float oc[8];
#pragma unroll
    for (int i = 0; i < 4; ++i) {
        oc[2*i]   = b2f((u16)(ou[i] & 0xFFFFu));
        oc[2*i+1] = b2f((u16)(ou[i] >> 16));
    }
    float acc[DOUT];
#pragma unroll
    for (int c = 0; c < DOUT; ++c) acc[c] = 0.f;
#pragma unroll
    for (int i = 0; i < 8; ++i) {
        int k = lane * 8 + i;
        float x = oc[i];
#pragma unroll
        for (int c = 0; c < DOUT; ++c) acc[c] += x * W4s[k * DOUT + c];
    }
#pragma unroll
    for (int off = 32; off >= 1; off >>= 1)
#pragma unroll
        for (int c = 0; c < DOUT; ++c) acc[c] += __shfl_xor(acc[c], off, 64);
    float mx = -1e30f;
#pragma unroll
    for (int c = 0; c < DOUT; ++c) { acc[c] += b4s[c]; mx = fmaxf(mx, acc[c]); }
    float sum = 0.f;
#pragma unroll
    for (int c = 0; c < DOUT; ++c) sum += __expf(acc[c] - mx);
    float lse = mx + logf(sum);
    if (lane == 0) {
#pragma unroll
        for (int c = 0; c < DOUT; ++c) out[row * DOUT + c] = acc[c] - lse;
    }
}

// ---------------------------------------------------------------------------
extern "C" void kernel_launch(void* const* d_in, const int* in_sizes, int n_in,
                              void* d_out, int out_size, void* d_ws, size_t ws_size,
                              hipStream_t stream) {
    const float* x  = (const float*)d_in[0];
    const float* gv = (const float*)d_in[1];
    const float* uv = (const float*)d_in[2];
    const float* W1 = (const float*)d_in[3];
    const float* b1 = (const float*)d_in[4];
    const float* W2 = (const float*)d_in[5];
    const float* b2 = (const float*)d_in[6];
    const float* W3 = (const float*)d_in[7];
    const float* b3 = (const float*)d_in[8];
    const float* W4 = (const float*)d_in[9];
    const float* b4 = (const float*)d_in[10];
    float* out = (float*)d_out;

    char* ws = (char*)d_ws;
    const size_t MB64 = (size_t)67108864;
    const size_t FULL_NEED = 3 * MB64 + 4194304;   // 196 MiB + weights

    if (ws_size >= FULL_NEED) {
        // Full-batch schedule: R0 h1->ctx | R1 h | R2 hT->o | R3 weights
        u16* h1  = (u16*)(ws);
        u16* h   = (u16*)(ws + MB64);
        u16* hT  = (u16*)(ws + 2 * MB64);
        u16* ctx = h1;
        u16* o   = hT;
        u16* W1t = (u16*)(ws + 3 * MB64);
        u16* W2t = W1t + 512 * 1024;
        u16* W3t = W2t + 1024 * 1024;

        transpose_cvt<<<dim3(32, 16), dim3(32, 8), 0, stream>>>(W1, W1t, 512, 1024);
        transpose_cvt<<<dim3(32, 32), dim3(32, 8), 0, stream>>>(W2, W2t, 1024, 1024);
        transpose_cvt<<<dim3(16, 32), dim3(32, 8), 0, stream>>>(W3, W3t, 1024, 512);

        gemm_bt_bias_relu<true ><<<dim3(256, 8), 256, 0, stream>>>(x,  W1t, b1, h1,
                                                                   32768, 1024, 512, 1);
        gemm_bt_bias_relu<false><<<dim3(256, 8), 256, 0, stream>>>(h1, W2t, b2, h,
                                                                   32768, 1024, 1024, 1);
        transpose_b<<<dim3(32, 64, 16), dim3(32, 8), 0, stream>>>(h, hT, 2048, 1024);
        flash_attn<<<dim3(128, 16), 256, 0, stream>>>(h, hT, ctx);
        gemm_bt_bias_relu<false><<<dim3(256, 4), 256, 0, stream>>>(ctx, W3t, b3, o,
                                                                   32768, 512, 1024, 1);
        head_logsoftmax<<<8192, 256, 0, stream>>>(o, W4, b4, out);
    } else {
        // Compact fallback (proven round-4 schedule, peak ~84 MiB)
        u16* h      = (u16*)(ws);
        u16* h1_buf = (u16*)(ws + MB64);
        u16* hT_b   = h1_buf;
        u16* ctx_b  = (u16*)(ws + MB64 + 4194304);
        u16* o_b    = (u16*)(ws + MB64 + 8388608);
        u16* W1t    = (u16*)(ws + (size_t)83886080);
        u16* W2t    = W1t + 512 * 1024;
        u16* W3t    = W2t + 1024 * 1024;

        transpose_cvt<<<dim3(32, 16), dim3(32, 8), 0, stream>>>(W1, W1t, 512, 1024);
        transpose_cvt<<<dim3(32, 32), dim3(32, 8), 0, stream>>>(W2, W2t, 1024, 1024);
        transpose_cvt<<<dim3(16, 32), dim3(32, 8), 0, stream>>>(W3, W3t, 1024, 512);

        for (int c = 0; c < 4; ++c) {
            const float* xc = x + (size_t)c * 8192 * DIN;
            u16*         hc = h + (size_t)c * 8192 * DH;
            gemm_bt_bias_relu<true ><<<dim3(64, 8), 256, 0, stream>>>(xc, W1t, b1, h1_buf,
                                                                      8192, 1024, 512, 1);
            gemm_bt_bias_relu<false><<<dim3(64, 8), 256, 0, stream>>>(h1_buf, W2t, b2, hc,
                                                                      8192, 1024, 1024, 1);
        }
        for (int b = 0; b < B_; ++b) {
            const u16* hb = h + (size_t)b * S_ * DH;
            transpose_b<<<dim3(32, 64, 1), dim3(32, 8), 0, stream>>>(hb, hT_b, 2048, 1024);
            flash_attn<<<dim3(128, 1), 256, 0, stream>>>(hb, hT_b, ctx_b);
            gemm_bt_bias_relu<false><<<dim3(16, 4), 256, 0, stream>>>(ctx_b, W3t, b3, o_b,
                                                                      2048, 512, 1024, 1);
            head_logsoftmax<<<512, 256, 0, stream>>>(o_b, W4, b4,
                                                     out + (size_t)b * S_ * DOUT);
        }
    }

    // pass-throughs (f32)
    size_t n_gv = (size_t)in_sizes[1], n_uv = (size_t)in_sizes[2];
    size_t o0 = (size_t)out_size - n_gv - n_uv;
    hipMemcpyAsync(out + o0,        gv, n_gv * 4, hipMemcpyDeviceToDevice, stream);
    hipMemcpyAsync(out + o0 + n_gv, uv, n_uv * 4, hipMemcpyDeviceToDevice, stream);
}

// Round 6
// 862.795 us; speedup vs baseline: 7.5533x; 2.0741x over previous
//
#include <hip/hip_runtime.h>
#include <stdint.h>

// Problem constants (fixed by reference)
#define B_   16
#define S_   2048
#define DIN  512
#define DH   1024
#define DOUT 10

typedef unsigned short u16;
typedef unsigned int   u32;

typedef __bf16 bf16_t;
typedef bf16_t bf16x8 __attribute__((ext_vector_type(8)));
typedef float  f32x4  __attribute__((ext_vector_type(4)));

#define MASKVAL (-3.0e4f)

__device__ __forceinline__ float b2f(u16 u) {
    union { u32 i; float f; } v; v.i = ((u32)u) << 16; return v.f;
}
__device__ __forceinline__ u16 f2b(float f) {
    union { float f; u32 i; } v; v.f = f;
    u32 u = v.i;
    u32 r = (u + 0x7FFFu + ((u >> 16) & 1u)) >> 16;  // RNE
    return (u16)r;
}
__device__ __forceinline__ u32 pack2(float a, float b) {
    return (u32)f2b(a) | ((u32)f2b(b) << 16);
}

__device__ __forceinline__ f32x4 mfma16(bf16x8 a, bf16x8 b, f32x4 c) {
    return __builtin_amdgcn_mfma_f32_16x16x32_bf16(a, b, c, 0, 0, 0);
}

// load 8 contiguous elements at element-index eidx as packed bf16x8 (uint4)
template<bool F32>
__device__ __forceinline__ uint4 ld8(const void* base, size_t eidx) {
    if constexpr (F32) {
        const float* p = (const float*)base + eidx;
        float4 f0 = *(const float4*)p;
        float4 f1 = *(const float4*)(p + 4);
        uint4 r;
        r.x = pack2(f0.x, f0.y); r.y = pack2(f0.z, f0.w);
        r.z = pack2(f1.x, f1.y); r.w = pack2(f1.z, f1.w);
        return r;
    } else {
        return *(const uint4*)((const u16*)base + eidx);
    }
}

// ---------------------------------------------------------------------------
// C[M,N] = relu(A[M,K] @ Bt[N,K]^T + bias[N]); A f32 or bf16 (AF32), Bt bf16,
// bias f32, C bf16, fp32 accum. 128x128 tile, BK=32, 4 waves, 4x4 MFMA/wave.
// ---------------------------------------------------------------------------
template<bool AF32>
__global__ __launch_bounds__(256) void gemm_bt_bias_relu(
    const void* __restrict__ A, const u16* __restrict__ Bt,
    const float* __restrict__ bias, u16* __restrict__ C,
    int M, int N, int K, int do_relu)
{
    __shared__ __attribute__((aligned(16))) u16 As[128 * 32];
    __shared__ __attribute__((aligned(16))) u16 Bs[128 * 32];

    const int tid  = threadIdx.x;
    const int lane = tid & 63;
    const int w    = tid >> 6;
    const int wm   = w >> 1, wn = w & 1;
    const int quad = lane >> 4, l15 = lane & 15;

    const int m0 = blockIdx.x * 128;
    const int n0 = blockIdx.y * 128;

    const int c0 = tid, c1 = tid + 256;
    size_t eA0 = (size_t)(m0 + (c0 >> 2)) * K + (c0 & 3) * 8;
    size_t eA1 = (size_t)(m0 + (c1 >> 2)) * K + (c1 & 3) * 8;
    size_t eB0 = (size_t)(n0 + (c0 >> 2)) * K + (c0 & 3) * 8;
    size_t eB1 = (size_t)(n0 + (c1 >> 2)) * K + (c1 & 3) * 8;

    f32x4 acc[4][4];
#pragma unroll
    for (int i = 0; i < 4; ++i)
#pragma unroll
        for (int j = 0; j < 4; ++j) acc[i][j] = (f32x4){0.f, 0.f, 0.f, 0.f};

    uint4 va0 = ld8<AF32>(A, eA0), va1 = ld8<AF32>(A, eA1);
    uint4 vb0 = ld8<false>(Bt, eB0), vb1 = ld8<false>(Bt, eB1);

    const int nk = K >> 5;
    for (int kk = 0; kk < nk; ++kk) {
        __syncthreads();
        *(uint4*)&As[c0 * 8] = va0;
        *(uint4*)&As[c1 * 8] = va1;
        *(uint4*)&Bs[c0 * 8] = vb0;
        *(uint4*)&Bs[c1 * 8] = vb1;
        if (kk + 1 < nk) {
            eA0 += 32; eA1 += 32; eB0 += 32; eB1 += 32;
            va0 = ld8<AF32>(A, eA0); va1 = ld8<AF32>(A, eA1);
            vb0 = ld8<false>(Bt, eB0); vb1 = ld8<false>(Bt, eB1);
        }
        __syncthreads();
        bf16x8 af[4], bfr[4];
#pragma unroll
        for (int i = 0; i < 4; ++i)
            af[i] = *(const bf16x8*)&As[(wm * 64 + i * 16 + l15) * 32 + quad * 8];
#pragma unroll
        for (int j = 0; j < 4; ++j)
            bfr[j] = *(const bf16x8*)&Bs[(wn * 64 + j * 16 + l15) * 32 + quad * 8];
#pragma unroll
        for (int i = 0; i < 4; ++i)
#pragma unroll
            for (int j = 0; j < 4; ++j)
                acc[i][j] = mfma16(af[i], bfr[j], acc[i][j]);
    }

    const int r0 = quad * 4;
#pragma unroll
    for (int j = 0; j < 4; ++j) {
        int col = n0 + wn * 64 + j * 16 + l15;
        float bv = bias[col];
#pragma unroll
        for (int i = 0; i < 4; ++i) {
            int rowb = m0 + wm * 64 + i * 16 + r0;
#pragma unroll
            for (int r = 0; r < 4; ++r) {
                float v = acc[i][j][r] + bv;
                if (do_relu) v = fmaxf(v, 0.f);
                C[(size_t)(rowb + r) * N + col] = f2b(v);
            }
        }
    }
}

// ---------------------------------------------------------------------------
// score_gemm: Sc[z][s][t] = mask(h[z][s]·h[z][t]) raw bf16 scores.
// M=N=S_, K=DH. Triangular block skip. grid (16,16,nb).
// ---------------------------------------------------------------------------
__global__ __launch_bounds__(256) void score_gemm(
    const u16* __restrict__ h, u16* __restrict__ Sc)
{
    __shared__ __attribute__((aligned(16))) u16 As[128 * 32];
    __shared__ __attribute__((aligned(16))) u16 Bs[128 * 32];

    const int m0 = blockIdx.x * 128;
    const int n0 = blockIdx.y * 128;
    if (n0 > m0 + 127) return;   // fully-masked block

    const u16* A = h  + (size_t)blockIdx.z * S_ * DH;
    u16*       C = Sc + (size_t)blockIdx.z * S_ * S_;

    const int tid  = threadIdx.x;
    const int lane = tid & 63;
    const int w    = tid >> 6;
    const int wm   = w >> 1, wn = w & 1;
    const int quad = lane >> 4, l15 = lane & 15;

    const int c0 = tid, c1 = tid + 256;
    size_t eA0 = (size_t)(m0 + (c0 >> 2)) * DH + (c0 & 3) * 8;
    size_t eA1 = (size_t)(m0 + (c1 >> 2)) * DH + (c1 & 3) * 8;
    size_t eB0 = (size_t)(n0 + (c0 >> 2)) * DH + (c0 & 3) * 8;
    size_t eB1 = (size_t)(n0 + (c1 >> 2)) * DH + (c1 & 3) * 8;

    f32x4 acc[4][4];
#pragma unroll
    for (int i = 0; i < 4; ++i)
#pragma unroll
        for (int j = 0; j < 4; ++j) acc[i][j] = (f32x4){0.f, 0.f, 0.f, 0.f};

    uint4 va0 = ld8<false>(A, eA0), va1 = ld8<false>(A, eA1);
    uint4 vb0 = ld8<false>(A, eB0), vb1 = ld8<false>(A, eB1);

    const int nk = DH >> 5;
    for (int kk = 0; kk < nk; ++kk) {
        __syncthreads();
        *(uint4*)&As[c0 * 8] = va0;
        *(uint4*)&As[c1 * 8] = va1;
        *(uint4*)&Bs[c0 * 8] = vb0;
        *(uint4*)&Bs[c1 * 8] = vb1;
        if (kk + 1 < nk) {
            eA0 += 32; eA1 += 32; eB0 += 32; eB1 += 32;
            va0 = ld8<false>(A, eA0); va1 = ld8<false>(A, eA1);
            vb0 = ld8<false>(A, eB0); vb1 = ld8<false>(A, eB1);
        }
        __syncthreads();
        bf16x8 af[4], bfr[4];
#pragma unroll
        for (int i = 0; i < 4; ++i)
            af[i] = *(const bf16x8*)&As[(wm * 64 + i * 16 + l15) * 32 + quad * 8];
#pragma unroll
        for (int j = 0; j < 4; ++j)
            bfr[j] = *(const bf16x8*)&Bs[(wn * 64 + j * 16 + l15) * 32 + quad * 8];
#pragma unroll
        for (int i = 0; i < 4; ++i)
#pragma unroll
            for (int j = 0; j < 4; ++j)
                acc[i][j] = mfma16(af[i], bfr[j], acc[i][j]);
    }

    const int r0 = quad * 4;
#pragma unroll
    for (int j = 0; j < 4; ++j) {
        int col = n0 + wn * 64 + j * 16 + l15;
#pragma unroll
        for (int i = 0; i < 4; ++i) {
            int rowb = m0 + wm * 64 + i * 16 + r0;
#pragma unroll
            for (int r = 0; r < 4; ++r) {
                int row = rowb + r;
                float v = (col <= row) ? acc[i][j][r] : MASKVAL;
                C[(size_t)row * S_ + col] = f2b(v);
            }
        }
    }
}

// ---------------------------------------------------------------------------
// softmax_rows: in-place row softmax of Sc (bf16), one wave per row of S_.
// grid = nrows/4, block 256.
// ---------------------------------------------------------------------------
__global__ __launch_bounds__(256) void softmax_rows(u16* __restrict__ Sc)
{
    const int tid = threadIdx.x;
    const int lane = tid & 63, w = tid >> 6;
    u16* p = Sc + ((size_t)blockIdx.x * 4 + w) * S_;
    float v[32];
    float m = -1e30f;
#pragma unroll
    for (int k = 0; k < 4; ++k) {
        uint4 u = *(const uint4*)&p[k * 512 + lane * 8];
        const u32* uu = (const u32*)&u;
#pragma unroll
        for (int i = 0; i < 4; ++i) {
            float a = b2f((u16)(uu[i] & 0xFFFFu));
            float b = b2f((u16)(uu[i] >> 16));
            v[k * 8 + 2 * i] = a; v[k * 8 + 2 * i + 1] = b;
            m = fmaxf(m, fmaxf(a, b));
        }
    }
#pragma unroll
    for (int off = 32; off >= 1; off >>= 1) m = fmaxf(m, __shfl_xor(m, off, 64));
    float s = 0.f;
#pragma unroll
    for (int i = 0; i < 32; ++i) { v[i] = __expf(v[i] - m); s += v[i]; }
#pragma unroll
    for (int off = 32; off >= 1; off >>= 1) s += __shfl_xor(s, off, 64);
    float inv = 1.0f / s;
#pragma unroll
    for (int k = 0; k < 4; ++k) {
        uint4 u; u32* uu = (u32*)&u;
#pragma unroll
        for (int i = 0; i < 4; ++i)
            uu[i] = pack2(v[k * 8 + 2 * i] * inv, v[k * 8 + 2 * i + 1] * inv);
        *(uint4*)&p[k * 512 + lane * 8] = u;
    }
}

// ---------------------------------------------------------------------------
// pv_gemm: ctx[z] = P[z] @ V[z], A=P [S_,S_] bf16, Bt=hT [DH,S_], C=[S_,DH].
// k-limit: P rows m0..m0+127 are zero beyond col m0+127 -> nk=(m0+128)/32.
// grid (16, 8, nb).
// ---------------------------------------------------------------------------
__global__ __launch_bounds__(256) void pv_gemm(
    const u16* __restrict__ P, const u16* __restrict__ hT, u16* __restrict__ ctx)
{
    __shared__ __attribute__((aligned(16))) u16 As[128 * 32];
    __shared__ __attribute__((aligned(16))) u16 Bs[128 * 32];

    const int m0 = blockIdx.x * 128;
    const int n0 = blockIdx.y * 128;
    const u16* A  = P   + (size_t)blockIdx.z * S_ * S_;
    const u16* Bt = hT  + (size_t)blockIdx.z * DH * S_;
    u16*       C  = ctx + (size_t)blockIdx.z * S_ * DH;

    const int tid  = threadIdx.x;
    const int lane = tid & 63;
    const int w    = tid >> 6;
    const int wm   = w >> 1, wn = w & 1;
    const int quad = lane >> 4, l15 = lane & 15;

    const int c0 = tid, c1 = tid + 256;
    size_t eA0 = (size_t)(m0 + (c0 >> 2)) * S_ + (c0 & 3) * 8;
    size_t eA1 = (size_t)(m0 + (c1 >> 2)) * S_ + (c1 & 3) * 8;
    size_t eB0 = (size_t)(n0 + (c0 >> 2)) * S_ + (c0 & 3) * 8;
    size_t eB1 = (size_t)(n0 + (c1 >> 2)) * S_ + (c1 & 3) * 8;

    f32x4 acc[4][4];
#pragma unroll
    for (int i = 0; i < 4; ++i)
#pragma unroll
        for (int j = 0; j < 4; ++j) acc[i][j] = (f32x4){0.f, 0.f, 0.f, 0.f};

    uint4 va0 = ld8<false>(A, eA0), va1 = ld8<false>(A, eA1);
    uint4 vb0 = ld8<false>(Bt, eB0), vb1 = ld8<false>(Bt, eB1);

    const int nk = (m0 + 128) >> 5;   // causal k-limit
    for (int kk = 0; kk < nk; ++kk) {
        __syncthreads();
        *(uint4*)&As[c0 * 8] = va0;
        *(uint4*)&As[c1 * 8] = va1;
        *(uint4*)&Bs[c0 * 8] = vb0;
        *(uint4*)&Bs[c1 * 8] = vb1;
        if (kk + 1 < nk) {
            eA0 += 32; eA1 += 32; eB0 += 32; eB1 += 32;
            va0 = ld8<false>(A, eA0); va1 = ld8<false>(A, eA1);
            vb0 = ld8<false>(Bt, eB0); vb1 = ld8<false>(Bt, eB1);
        }
        __syncthreads();
        bf16x8 af[4], bfr[4];
#pragma unroll
        for (int i = 0; i < 4; ++i)
            af[i] = *(const bf16x8*)&As[(wm * 64 + i * 16 + l15) * 32 + quad * 8];
#pragma unroll
        for (int j = 0; j < 4; ++j)
            bfr[j] = *(const bf16x8*)&Bs[(wn * 64 + j * 16 + l15) * 32 + quad * 8];
#pragma unroll
        for (int i = 0; i < 4; ++i)
#pragma unroll
            for (int j = 0; j < 4; ++j)
                acc[i][j] = mfma16(af[i], bfr[j], acc[i][j]);
    }

    const int r0 = quad * 4;
#pragma unroll
    for (int j = 0; j < 4; ++j) {
        int col = n0 + wn * 64 + j * 16 + l15;
#pragma unroll
        for (int i = 0; i < 4; ++i) {
            int rowb = m0 + wm * 64 + i * 16 + r0;
#pragma unroll
            for (int r = 0; r < 4; ++r)
                C[(size_t)(rowb + r) * DH + col] = f2b(acc[i][j][r]);
        }
    }
}

// ---------------------------------------------------------------------------
// transpose + f32->bf16 convert: in f32 [R][C] -> out bf16 [C][R]. block (32,8)
// ---------------------------------------------------------------------------
__global__ __launch_bounds__(256) void transpose_cvt(
    const float* __restrict__ in, u16* __restrict__ out, int R, int C)
{
    __shared__ u16 t[32][33];
    int c0 = blockIdx.x * 32, r0 = blockIdx.y * 32;
    int tx = threadIdx.x, ty = threadIdx.y;
#pragma unroll
    for (int i = 0; i < 4; ++i)
        t[ty + i * 8][tx] = f2b(in[(size_t)(r0 + ty + i * 8) * C + c0 + tx]);
    __syncthreads();
#pragma unroll
    for (int i = 0; i < 4; ++i)
        out[(size_t)(c0 + ty + i * 8) * R + r0 + tx] = t[tx][ty + i * 8];
}

// batched bf16 transpose: in [z][R][C] -> out [z][C][R]. block (32,8)
__global__ __launch_bounds__(256) void transpose_b(
    const u16* __restrict__ in, u16* __restrict__ out, int R, int C)
{
    __shared__ u16 t[32][33];
    const u16* ip = in  + (size_t)blockIdx.z * R * C;
    u16*       op = out + (size_t)blockIdx.z * R * C;
    int c0 = blockIdx.x * 32, r0 = blockIdx.y * 32;
    int tx = threadIdx.x, ty = threadIdx.y;
#pragma unroll
    for (int i = 0; i < 4; ++i)
        t[ty + i * 8][tx] = ip[(size_t)(r0 + ty + i * 8) * C + c0 + tx];
    __syncthreads();
#pragma unroll
    for (int i = 0; i < 4; ++i)
        op[(size_t)(c0 + ty + i * 8) * R + r0 + tx] = t[tx][ty + i * 8];
}

// ---------------------------------------------------------------------------
// head: out[row,:] = log_softmax(o[row,:] @ W4 + b4). One wave per row.
// ---------------------------------------------------------------------------
__global__ __launch_bounds__(256) void head_logsoftmax(
    const u16* __restrict__ o, const float* __restrict__ W4,
    const float* __restrict__ b4, float* __restrict__ out)
{
    __shared__ float W4s[DIN * DOUT];
    __shared__ float b4s[DOUT];
    const int tid = threadIdx.x;
    for (int i = tid; i < DIN * DOUT; i += 256) W4s[i] = W4[i];
    if (tid < DOUT) b4s[tid] = b4[tid];
    __syncthreads();
    const int lane = tid & 63, w = tid >> 6;
    const size_t row = (size_t)blockIdx.x * 4 + w;
    const uint4 ov = *(const uint4*)&o[row * DIN + lane * 8];
    const u32* ou = (const u32*)&ov;
    float oc[8];
#pragma unroll
    for (int i = 0; i < 4; ++i) {
        oc[2*i]   = b2f((u16)(ou[i] & 0xFFFFu));
        oc[2*i+1] = b2f((u16)(ou[i] >> 16));
    }
    float acc[DOUT];
#pragma unroll
    for (int c = 0; c < DOUT; ++c) acc[c] = 0.f;
#pragma unroll
    for (int i = 0; i < 8; ++i) {
        int k = lane * 8 + i;
        float x = oc[i];
#pragma unroll
        for (int c = 0; c < DOUT; ++c) acc[c] += x * W4s[k * DOUT + c];
    }
#pragma unroll
    for (int off = 32; off >= 1; off >>= 1)
#pragma unroll
        for (int c = 0; c < DOUT; ++c) acc[c] += __shfl_xor(acc[c], off, 64);
    float mx = -1e30f;
#pragma unroll
    for (int c = 0; c < DOUT; ++c) { acc[c] += b4s[c]; mx = fmaxf(mx, acc[c]); }
    float sum = 0.f;
#pragma unroll
    for (int c = 0; c < DOUT; ++c) sum += __expf(acc[c] - mx);
    float lse = mx + logf(sum);
    if (lane == 0) {
#pragma unroll
        for (int c = 0; c < DOUT; ++c) out[row * DOUT + c] = acc[c] - lse;
    }
}

// ---------------------------------------------------------------------------
extern "C" void kernel_launch(void* const* d_in, const int* in_sizes, int n_in,
                              void* d_out, int out_size, void* d_ws, size_t ws_size,
                              hipStream_t stream) {
    const float* x  = (const float*)d_in[0];
    const float* gv = (const float*)d_in[1];
    const float* uv = (const float*)d_in[2];
    const float* W1 = (const float*)d_in[3];
    const float* b1 = (const float*)d_in[4];
    const float* W2 = (const float*)d_in[5];
    const float* b2 = (const float*)d_in[6];
    const float* W3 = (const float*)d_in[7];
    const float* b3 = (const float*)d_in[8];
    const float* W4 = (const float*)d_in[9];
    const float* b4 = (const float*)d_in[10];
    float* out = (float*)d_out;

    char* ws = (char*)d_ws;
    const size_t MB64 = (size_t)67108864;
    const size_t MiB  = (size_t)1048576;
    const size_t FULL_NEED = 3 * MB64 + 5 * MiB;   // proven envelope

    if (ws_size >= FULL_NEED) {
        // R0: h1 -> ctx (64Mi) | R1: h (64Mi) | R2: {hT_c 16Mi + P_c 34Mi} -> o | R3: weights
        u16* h1  = (u16*)(ws);
        u16* h   = (u16*)(ws + MB64);
        u16* ctx = h1;
        u16* hT_c = (u16*)(ws + 2 * MB64);
        u16* P_c  = (u16*)(ws + 2 * MB64 + 16 * MiB);
        u16* o    = (u16*)(ws + 2 * MB64);
        u16* W1t = (u16*)(ws + 3 * MB64);
        u16* W2t = W1t + 512 * 1024;
        u16* W3t = W2t + 1024 * 1024;

        transpose_cvt<<<dim3(32, 16), dim3(32, 8), 0, stream>>>(W1, W1t, 512, 1024);
        transpose_cvt<<<dim3(32, 32), dim3(32, 8), 0, stream>>>(W2, W2t, 1024, 1024);
        transpose_cvt<<<dim3(16, 32), dim3(32, 8), 0, stream>>>(W3, W3t, 1024, 512);

        gemm_bt_bias_relu<true ><<<dim3(256, 8), 256, 0, stream>>>(x,  W1t, b1, h1,
                                                                   32768, 1024, 512, 1);
        gemm_bt_bias_relu<false><<<dim3(256, 8), 256, 0, stream>>>(h1, W2t, b2, h,
                                                                   32768, 1024, 1024, 1);

        // attention in 4 chunks of 4 batches
        for (int c = 0; c < 4; ++c) {
            const u16* hc  = h   + (size_t)c * 4 * S_ * DH;
            u16*       cxc = ctx + (size_t)c * 4 * S_ * DH;
            transpose_b<<<dim3(32, 64, 4), dim3(32, 8), 0, stream>>>(hc, hT_c, 2048, 1024);
            score_gemm<<<dim3(16, 16, 4), 256, 0, stream>>>(hc, P_c);
            softmax_rows<<<2048, 256, 0, stream>>>(P_c);
            pv_gemm<<<dim3(16, 8, 4), 256, 0, stream>>>(P_c, hT_c, cxc);
        }

        gemm_bt_bias_relu<false><<<dim3(256, 4), 256, 0, stream>>>(ctx, W3t, b3, o,
                                                                   32768, 512, 1024, 1);
        head_logsoftmax<<<8192, 256, 0, stream>>>(o, W4, b4, out);
    } else {
        // Compact fallback (~86 MiB): per-batch attention through small scratch
        u16* h    = (u16*)(ws);                          // 64 Mi
        u16* hT_b = (u16*)(ws + MB64);                   // 4 Mi
        u16* P_b  = (u16*)(ws + MB64 + 4 * MiB);         // 8 Mi
        u16* ctx_b= (u16*)(ws + MB64 + 12 * MiB);        // 4 Mi
        u16* o_b  = (u16*)(ws + MB64 + 16 * MiB);        // 2 Mi
        u16* W1t  = (u16*)(ws + MB64 + 18 * MiB);
        u16* W2t  = W1t + 512 * 1024;
        u16* W3t  = W2t + 1024 * 1024;
        u16* h1_b = P_b;   // 8 Mi region reused for GEMM1 chunks (4096 rows)

        transpose_cvt<<<dim3(32, 16), dim3(32, 8), 0, stream>>>(W1, W1t, 512, 1024);
        transpose_cvt<<<dim3(32, 32), dim3(32, 8), 0, stream>>>(W2, W2t, 1024, 1024);
        transpose_cvt<<<dim3(16, 32), dim3(32, 8), 0, stream>>>(W3, W3t, 1024, 512);

        for (int c = 0; c < 8; ++c) {
            const float* xc = x + (size_t)c * 4096 * DIN;
            u16*         hc = h + (size_t)c * 4096 * DH;
            gemm_bt_bias_relu<true ><<<dim3(32, 8), 256, 0, stream>>>(xc, W1t, b1, h1_b,
                                                                      4096, 1024, 512, 1);
            gemm_bt_bias_relu<false><<<dim3(32, 8), 256, 0, stream>>>(h1_b, W2t, b2, hc,
                                                                      4096, 1024, 1024, 1);
        }
        for (int b = 0; b < B_; ++b) {
            const u16* hb = h + (size_t)b * S_ * DH;
            transpose_b<<<dim3(32, 64, 1), dim3(32, 8), 0, stream>>>(hb, hT_b, 2048, 1024);
            score_gemm<<<dim3(16, 16, 1), 256, 0, stream>>>(hb, P_b);
            softmax_rows<<<512, 256, 0, stream>>>(P_b);
            pv_gemm<<<dim3(16, 8, 1), 256, 0, stream>>>(P_b, hT_b, ctx_b);
            gemm_bt_bias_relu<false><<<dim3(16, 4), 256, 0, stream>>>(ctx_b, W3t, b3, o_b,
                                                                      2048, 512, 1024, 1);
            head_logsoftmax<<<512, 256, 0, stream>>>(o_b, W4, b4,
                                                     out + (size_t)b * S_ * DOUT);
        }
    }

    // pass-throughs (f32)
    size_t n_gv = (size_t)in_sizes[1], n_uv = (size_t)in_sizes[2];
    size_t o0 = (size_t)out_size - n_gv - n_uv;
    hipMemcpyAsync(out + o0,        gv, n_gv * 4, hipMemcpyDeviceToDevice, stream);
    hipMemcpyAsync(out + o0 + n_gv, uv, n_uv * 4, hipMemcpyDeviceToDevice, stream);
}